// Round 1
// baseline (43.644 us; speedup 1.0000x reference)
//
#include <hip/hip_runtime.h>

// DCN cross stack, algebraically collapsed:
//   x_k = c_k * x0 + d_k,  d_k = sum_{j<k} b_j (row-independent)
//   u_k = x0 . w_k,  e_k = d_k . w_k,  c_{k+1} = c_k*(1+u_k) + e_k, c_0 = 1
//   out = c_L * (x0 @ W_out) + (d_L @ W_out + b_out)
// => per row: 12 dots of length 512 (a tall-skinny GEMV) + scalar recurrence.

typedef float v4f __attribute__((ext_vector_type(4)));

template<int CTRL>
__device__ __forceinline__ float dpp_add(float v) {
  int t = __builtin_amdgcn_update_dpp(0, __float_as_int(v), CTRL, 0xF, 0xF, true);
  return v + __int_as_float(t);
}

// Full-wave (64 lane) sum; total lands in lane 63. VALU-only (DPP), no LDS pipe.
__device__ __forceinline__ float wave_reduce(float v) {
  v = dpp_add<0x111>(v); // row_shr:1
  v = dpp_add<0x112>(v); // row_shr:2
  v = dpp_add<0x114>(v); // row_shr:4
  v = dpp_add<0x118>(v); // row_shr:8  -> lane15 of each row-of-16 has row sum
  v = dpp_add<0x142>(v); // row_bcast:15 -> lane31 has sum of 32
  v = dpp_add<0x143>(v); // row_bcast:31 -> lane63 has sum of 64
  return v;
}

__global__ __launch_bounds__(256) void cross_fused(
    const float* __restrict__ x, const float* __restrict__ cw,
    const float* __restrict__ cb, const float* __restrict__ Wo,
    const float* __restrict__ bo, float* __restrict__ out, int B)
{
  const int F = 512, T = 8;
  const int lane = threadIdx.x & 63;
  const int wid  = blockIdx.x * (blockDim.x >> 6) + (threadIdx.x >> 6);
  const int nw   = gridDim.x * (blockDim.x >> 6);
  const int f0 = 4 * lane;        // owned quad 1: f0..f0+3
  const int f1 = 256 + 4 * lane;  // owned quad 2

  // ---- hoist all weights into VGPRs (once per wave; tiny L2-hit traffic) ----
  v4f wA[4], wB[4], bA[4], bB[4];
  #pragma unroll
  for (int k = 0; k < 4; ++k) {
    wA[k] = *(const v4f*)(cw + k * F + f0);
    wB[k] = *(const v4f*)(cw + k * F + f1);
    bA[k] = *(const v4f*)(cb + k * F + f0);
    bB[k] = *(const v4f*)(cb + k * F + f1);
  }
  v4f WoA[4][2], WoB[4][2];
  #pragma unroll
  for (int e = 0; e < 4; ++e) {
    WoA[e][0] = *(const v4f*)(Wo + (f0 + e) * T);
    WoA[e][1] = *(const v4f*)(Wo + (f0 + e) * T + 4);
    WoB[e][0] = *(const v4f*)(Wo + (f1 + e) * T);
    WoB[e][1] = *(const v4f*)(Wo + (f1 + e) * T + 4);
  }

  // ---- per-wave constants: e_k = d_k.w_k, g_t = d_4.Wout[:,t] + bo[t] ----
  float e1p = 0.f, e2p = 0.f, e3p = 0.f;
  float gp[8];
  #pragma unroll
  for (int t = 0; t < 8; ++t) gp[t] = 0.f;
  #pragma unroll
  for (int e = 0; e < 4; ++e) {
    float d1 = bA[0][e], d2 = d1 + bA[1][e], d3 = d2 + bA[2][e], d4 = d3 + bA[3][e];
    e1p += d1 * wA[1][e];
    e2p += d2 * wA[2][e];
    e3p += d3 * wA[3][e];
    #pragma unroll
    for (int t = 0; t < 4; ++t) { gp[t] += d4 * WoA[e][0][t]; gp[t + 4] += d4 * WoA[e][1][t]; }
    float s1 = bB[0][e], s2 = s1 + bB[1][e], s3 = s2 + bB[2][e], s4 = s3 + bB[3][e];
    e1p += s1 * wB[1][e];
    e2p += s2 * wB[2][e];
    e3p += s3 * wB[3][e];
    #pragma unroll
    for (int t = 0; t < 4; ++t) { gp[t] += s4 * WoB[e][0][t]; gp[t + 4] += s4 * WoB[e][1][t]; }
  }
  const float e1 = wave_reduce(e1p);
  const float e2 = wave_reduce(e2p);
  const float e3 = wave_reduce(e3p);
  float g[8];
  #pragma unroll
  for (int t = 0; t < 8; ++t) g[t] = wave_reduce(gp[t]) + bo[t];  // valid in lane 63

  // ---- row loop: 2 coalesced float4 loads per row, register prefetch ----
  const v4f* xp = (const v4f*)x;
  int row = wid;
  v4f xa, xb;
  if (row < B) {
    xa = xp[(size_t)row * 128 + lane];
    xb = xp[(size_t)row * 128 + 64 + lane];
  }
  while (row < B) {
    const int nrow = row + nw;
    v4f na, nb;
    if (nrow < B) {
      na = xp[(size_t)nrow * 128 + lane];
      nb = xp[(size_t)nrow * 128 + 64 + lane];
    }
    float u0 = 0.f, u1 = 0.f, u2 = 0.f, u3 = 0.f;
    float vv[8];
    #pragma unroll
    for (int t = 0; t < 8; ++t) vv[t] = 0.f;
    #pragma unroll
    for (int e = 0; e < 4; ++e) {
      const float xe = xa[e];
      u0 += xe * wA[0][e]; u1 += xe * wA[1][e];
      u2 += xe * wA[2][e]; u3 += xe * wA[3][e];
      #pragma unroll
      for (int t = 0; t < 4; ++t) { vv[t] += xe * WoA[e][0][t]; vv[t + 4] += xe * WoA[e][1][t]; }
      const float ye = xb[e];
      u0 += ye * wB[0][e]; u1 += ye * wB[1][e];
      u2 += ye * wB[2][e]; u3 += ye * wB[3][e];
      #pragma unroll
      for (int t = 0; t < 4; ++t) { vv[t] += ye * WoB[e][0][t]; vv[t + 4] += ye * WoB[e][1][t]; }
    }
    u0 = wave_reduce(u0); u1 = wave_reduce(u1);
    u2 = wave_reduce(u2); u3 = wave_reduce(u3);
    #pragma unroll
    for (int t = 0; t < 8; ++t) vv[t] = wave_reduce(vv[t]);

    float c = 1.f;
    c = fmaf(c, u0, c);        // e_0 = 0
    c = fmaf(c, u1, c) + e1;
    c = fmaf(c, u2, c) + e2;
    c = fmaf(c, u3, c) + e3;
    if (lane == 63) {
      v4f o0, o1;
      #pragma unroll
      for (int t = 0; t < 4; ++t) {
        o0[t] = fmaf(c, vv[t], g[t]);
        o1[t] = fmaf(c, vv[t + 4], g[t + 4]);
      }
      *(v4f*)(out + (size_t)row * 8) = o0;
      *(v4f*)(out + (size_t)row * 8 + 4) = o1;
    }
    xa = na; xb = nb; row = nrow;
  }
}

extern "C" void kernel_launch(void* const* d_in, const int* in_sizes, int n_in,
                              void* d_out, int out_size, void* d_ws, size_t ws_size,
                              hipStream_t stream) {
  const float* x  = (const float*)d_in[0];
  const float* cw = (const float*)d_in[1];
  const float* cb = (const float*)d_in[2];
  const float* Wo = (const float*)d_in[3];
  const float* bo = (const float*)d_in[4];
  float* out = (float*)d_out;
  const int B = in_sizes[0] / 512;  // 65536
  // 2048 blocks x 4 waves = 8192 waves -> 8 rows/wave grid-stride
  hipLaunchKernelGGL(cross_fused, dim3(2048), dim3(256), 0, stream,
                     x, cw, cb, Wo, bo, out, B);
}